// Round 1
// baseline (1038.207 us; speedup 1.0000x reference)
//
#include <hip/hip_runtime.h>
#include <hip/hip_bf16.h>
#include <stdint.h>

// Problem: B=64, T=512, D=2048, H=512
//   Uh   = text @ Ua + ba                 [B,H]
//   s    = tanh(frames@Wa + Uh) . Va      [B,T]
//   att  = softmax_T(s)                   [B,T]
//   out  = att . frames                   [B,D]
#define B_ 64
#define T_ 512
#define D_ 2048
#define H_ 512

typedef __bf16 bf16x8 __attribute__((ext_vector_type(8)));
typedef float floatx4 __attribute__((ext_vector_type(4)));

__device__ __forceinline__ unsigned short f2bf(float f) {
  unsigned int u = __float_as_uint(f);
  return (unsigned short)((u + 0x7FFFu + ((u >> 16) & 1u)) >> 16);  // RNE
}
__device__ __forceinline__ unsigned int pack2(float a, float b) {
  return (unsigned int)f2bf(a) | ((unsigned int)f2bf(b) << 16);
}

// ---------------------------------------------------------------------------
// Kernel 0: Wa [D][H] fp32 -> WaT [H][D] bf16  (so GEMM B-operand is
// k-contiguous; avoids scattered LDS writes in the hot loop)
// ---------------------------------------------------------------------------
__global__ void k_transpose_wa(const float* __restrict__ Wa,
                               unsigned short* __restrict__ WaT) {
  __shared__ float t[32][33];
  int h0 = blockIdx.x * 32;
  int d0 = blockIdx.y * 32;
  int j  = threadIdx.x & 31;
  int i0 = threadIdx.x >> 5;  // 0..7
#pragma unroll
  for (int ii = 0; ii < 4; ii++) {
    int i = i0 + ii * 8;
    t[i][j] = Wa[(size_t)(d0 + i) * H_ + h0 + j];
  }
  __syncthreads();
#pragma unroll
  for (int jj = 0; jj < 4; jj++) {
    int r = i0 + jj * 8;
    WaT[(size_t)(h0 + r) * D_ + d0 + j] = f2bf(t[j][r]);
  }
}

// ---------------------------------------------------------------------------
// Kernel 1: UhB[b][h] = sum_d text[b][d]*Ua[d][h] + ba[h]   (fp32, tiny)
// grid (H/256, B/8); 8-batch register blocking, Ua reads coalesced.
// ---------------------------------------------------------------------------
__global__ void k_uh(const float* __restrict__ text, const float* __restrict__ Ua,
                     const float* __restrict__ ba, float* __restrict__ UhB) {
  int h  = blockIdx.x * 256 + threadIdx.x;
  int b0 = blockIdx.y * 8;
  float acc[8] = {0.f, 0.f, 0.f, 0.f, 0.f, 0.f, 0.f, 0.f};
  for (int d = 0; d < D_; d++) {
    float ua = Ua[(size_t)d * H_ + h];
#pragma unroll
    for (int i = 0; i < 8; i++)
      acc[i] = fmaf(text[(b0 + i) * D_ + d], ua, acc[i]);
  }
  float bav = ba[h];
#pragma unroll
  for (int i = 0; i < 8; i++) UhB[(b0 + i) * H_ + h] = acc[i] + bav;
}

// ---------------------------------------------------------------------------
// Kernel 2: fused score GEMM.
// C[r][h] = frames_flat[r][:] @ Wa[:][h]   (r = b*T+t, M=32768, N=512, K=2048)
// epilogue: scores[r] += sum_h tanh(C+UhB)*Va  over this block's 128 h-cols.
// Tile 128x128xBK64, 4 waves (2x2 of 64x64), mfma 16x16x32 bf16.
// LDS stride 72 bf16 (=144B) -> ds_read_b128 lands 2 lanes/bank (free).
// tanh split over h-blocks is exact (elementwise); partials via atomicAdd.
// ---------------------------------------------------------------------------
__launch_bounds__(256, 2)
__global__ void k_scores(const float* __restrict__ frames,
                         const unsigned short* __restrict__ WaT,
                         const float* __restrict__ UhB,
                         const float* __restrict__ Va,
                         float* __restrict__ scores) {
  __shared__ __align__(16) unsigned short ldsA[128 * 72];
  __shared__ __align__(16) unsigned short ldsB[128 * 72];
  const int tid  = threadIdx.x;
  const int lane = tid & 63, wave = tid >> 6;
  const int wm = wave >> 1, wn = wave & 1;
  const int lr = lane & 15, q = lane >> 4;
  const int mBase = blockIdx.x * 128;   // 256 blocks: within one b (128|512)
  const int hBase = blockIdx.y * 128;   // 4 h-blocks

  floatx4 acc[4][4];
#pragma unroll
  for (int mi = 0; mi < 4; mi++)
#pragma unroll
    for (int ni = 0; ni < 4; ni++) acc[mi][ni] = (floatx4){0.f, 0.f, 0.f, 0.f};

  for (int k0 = 0; k0 < D_; k0 += 64) {
    // Stage A: frames rows, fp32 -> bf16 convert. 128 rows x 8 octets.
#pragma unroll
    for (int i = 0; i < 4; i++) {
      int task = i * 256 + tid;
      int m = task >> 3, oct = task & 7;
      const float* src = frames + (size_t)(mBase + m) * D_ + k0 + oct * 8;
      float4 p0 = ((const float4*)src)[0];
      float4 p1 = ((const float4*)src)[1];
      uint4 w;
      w.x = pack2(p0.x, p0.y); w.y = pack2(p0.z, p0.w);
      w.z = pack2(p1.x, p1.y); w.w = pack2(p1.z, p1.w);
      *reinterpret_cast<uint4*>(&ldsA[m * 72 + oct * 8]) = w;
    }
    // Stage B: WaT already bf16 + k-contiguous -> straight 16B copies.
#pragma unroll
    for (int i = 0; i < 4; i++) {
      int task = i * 256 + tid;
      int n = task >> 3, oct = task & 7;
      uint4 w = *reinterpret_cast<const uint4*>(
          WaT + (size_t)(hBase + n) * D_ + k0 + oct * 8);
      *reinterpret_cast<uint4*>(&ldsB[n * 72 + oct * 8]) = w;
    }
    __syncthreads();
#pragma unroll
    for (int kk = 0; kk < 2; kk++) {
      bf16x8 af[4], bfr[4];
#pragma unroll
      for (int mi = 0; mi < 4; mi++)
        af[mi] = *reinterpret_cast<const bf16x8*>(
            &ldsA[(wm * 64 + mi * 16 + lr) * 72 + kk * 32 + q * 8]);
#pragma unroll
      for (int ni = 0; ni < 4; ni++)
        bfr[ni] = *reinterpret_cast<const bf16x8*>(
            &ldsB[(wn * 64 + ni * 16 + lr) * 72 + kk * 32 + q * 8]);
#pragma unroll
      for (int mi = 0; mi < 4; mi++)
#pragma unroll
        for (int ni = 0; ni < 4; ni++)
          acc[mi][ni] = __builtin_amdgcn_mfma_f32_16x16x32_bf16(
              af[mi], bfr[ni], acc[mi][ni], 0, 0, 0);
    }
    __syncthreads();
  }

  // Epilogue. b is block-uniform (128-row tile never crosses b boundary).
  const int b = mBase >> 9;  // /T_
  float uhv[4], vav[4];
#pragma unroll
  for (int ni = 0; ni < 4; ni++) {
    int h = hBase + wn * 64 + ni * 16 + lr;
    uhv[ni] = UhB[b * H_ + h];
    vav[ni] = Va[h];
  }
  const int rowBase = mBase + wm * 64;
#pragma unroll
  for (int mi = 0; mi < 4; mi++) {
#pragma unroll
    for (int reg = 0; reg < 4; reg++) {
      float s = 0.f;
#pragma unroll
      for (int ni = 0; ni < 4; ni++) {
        float x = acc[mi][ni][reg] + uhv[ni];
        // tanh(x) = 1 - 2/(exp(2x)+1): inf-safe at both extremes
        float e = __expf(2.f * x);
        s += (1.f - 2.f / (e + 1.f)) * vav[ni];
      }
      s += __shfl_xor(s, 1, 16);
      s += __shfl_xor(s, 2, 16);
      s += __shfl_xor(s, 4, 16);
      s += __shfl_xor(s, 8, 16);
      if (lr == 0)
        atomicAdd(&scores[rowBase + mi * 16 + q * 4 + reg], s);
    }
  }
}

// ---------------------------------------------------------------------------
// Kernel 3: softmax over T per batch. grid=B, block=256 (2 elems/thread).
// ---------------------------------------------------------------------------
__global__ void k_softmax(const float* __restrict__ scores, float* __restrict__ att) {
  __shared__ float red[4];
  int b = blockIdx.x, tid = threadIdx.x;
  int lane = tid & 63, wave = tid >> 6;
  float s0 = scores[b * T_ + tid];
  float s1 = scores[b * T_ + 256 + tid];
  float mx = fmaxf(s0, s1);
#pragma unroll
  for (int off = 32; off; off >>= 1) mx = fmaxf(mx, __shfl_xor(mx, off, 64));
  if (lane == 0) red[wave] = mx;
  __syncthreads();
  mx = fmaxf(fmaxf(red[0], red[1]), fmaxf(red[2], red[3]));
  __syncthreads();
  float e0 = __expf(s0 - mx), e1 = __expf(s1 - mx);
  float sm = e0 + e1;
#pragma unroll
  for (int off = 32; off; off >>= 1) sm += __shfl_xor(sm, off, 64);
  if (lane == 0) red[wave] = sm;
  __syncthreads();
  sm = red[0] + red[1] + red[2] + red[3];
  float inv = 1.f / sm;
  att[b * T_ + tid]       = e0 * inv;
  att[b * T_ + 256 + tid] = e1 * inv;
}

// ---------------------------------------------------------------------------
// Kernel 4: out[b][d] = sum_t att[b][t] * frames[b][t][d]. HBM-bound stream.
// grid (D/1024, B), block 256, float4/lane, t unrolled x4 for MLP.
// ---------------------------------------------------------------------------
__global__ void k_wsum(const float* __restrict__ frames, const float* __restrict__ att,
                       float* __restrict__ out) {
  int b  = blockIdx.y;
  int d0 = blockIdx.x * 1024 + threadIdx.x * 4;
  const float* fp = frames + (size_t)b * T_ * D_ + d0;
  const float* ap = att + b * T_;
  float4 acc = {0.f, 0.f, 0.f, 0.f};
  for (int t = 0; t < T_; t += 4) {
    float a0 = ap[t], a1 = ap[t + 1], a2 = ap[t + 2], a3 = ap[t + 3];
    float4 v0 = *(const float4*)(fp + (size_t)(t + 0) * D_);
    float4 v1 = *(const float4*)(fp + (size_t)(t + 1) * D_);
    float4 v2 = *(const float4*)(fp + (size_t)(t + 2) * D_);
    float4 v3 = *(const float4*)(fp + (size_t)(t + 3) * D_);
    acc.x += a0 * v0.x + a1 * v1.x + a2 * v2.x + a3 * v3.x;
    acc.y += a0 * v0.y + a1 * v1.y + a2 * v2.y + a3 * v3.y;
    acc.z += a0 * v0.z + a1 * v1.z + a2 * v2.z + a3 * v3.z;
    acc.w += a0 * v0.w + a1 * v1.w + a2 * v2.w + a3 * v3.w;
  }
  *(float4*)(out + (size_t)b * D_ + d0) = acc;
}

// ---------------------------------------------------------------------------
extern "C" void kernel_launch(void* const* d_in, const int* in_sizes, int n_in,
                              void* d_out, int out_size, void* d_ws, size_t ws_size,
                              hipStream_t stream) {
  const float* frames = (const float*)d_in[0];
  const float* text   = (const float*)d_in[1];
  const float* Wa     = (const float*)d_in[2];
  const float* Ua     = (const float*)d_in[3];
  const float* Va     = (const float*)d_in[4];
  const float* ba     = (const float*)d_in[5];
  float* out = (float*)d_out;

  char* ws = (char*)d_ws;
  unsigned short* WaT = (unsigned short*)ws;                      // 2 MB
  float* UhB    = (float*)(ws + (size_t)(2u << 20));              // 128 KB
  float* scores = (float*)(ws + (size_t)(2u << 20) + (128u << 10));
  float* att    = (float*)(ws + (size_t)(2u << 20) + (256u << 10));

  k_transpose_wa<<<dim3(H_ / 32, D_ / 32), 256, 0, stream>>>(Wa, WaT);
  k_uh<<<dim3(H_ / 256, B_ / 8), 256, 0, stream>>>(text, Ua, ba, UhB);
  (void)hipMemsetAsync(scores, 0, (size_t)B_ * T_ * sizeof(float), stream);
  k_scores<<<dim3((B_ * T_) / 128, H_ / 128), 256, 0, stream>>>(frames, WaT, UhB, Va, scores);
  k_softmax<<<B_, 256, 0, stream>>>(scores, att);
  k_wsum<<<dim3(D_ / 1024, B_), 256, 0, stream>>>(frames, att, out);
}

// Round 2
// 630.474 us; speedup vs baseline: 1.6467x; 1.6467x over previous
//
#include <hip/hip_runtime.h>
#include <hip/hip_bf16.h>
#include <stdint.h>

// Problem: B=64, T=512, D=2048, H=512
//   Uh   = text @ Ua + ba                 [B,H]
//   s    = tanh(frames@Wa + Uh) . Va      [B,T]
//   att  = softmax_T(s)                   [B,T]
//   out  = att . frames                   [B,D]
#define B_ 64
#define T_ 512
#define D_ 2048
#define H_ 512

typedef __bf16 bf16x8 __attribute__((ext_vector_type(8)));
typedef float floatx4 __attribute__((ext_vector_type(4)));

__device__ __forceinline__ unsigned short f2bf(float f) {
  unsigned int u = __float_as_uint(f);
  return (unsigned short)((u + 0x7FFFu + ((u >> 16) & 1u)) >> 16);  // RNE
}
__device__ __forceinline__ unsigned int pack2(float a, float b) {
  return (unsigned int)f2bf(a) | ((unsigned int)f2bf(b) << 16);
}

// ---------------------------------------------------------------------------
// Kernel 0: Wa [D][H] fp32 -> WaT [H][D] bf16  (GEMM B-operand k-contiguous)
// ---------------------------------------------------------------------------
__global__ void k_transpose_wa(const float* __restrict__ Wa,
                               unsigned short* __restrict__ WaT) {
  __shared__ float t[32][33];
  int h0 = blockIdx.x * 32;
  int d0 = blockIdx.y * 32;
  int j  = threadIdx.x & 31;
  int i0 = threadIdx.x >> 5;  // 0..7
#pragma unroll
  for (int ii = 0; ii < 4; ii++) {
    int i = i0 + ii * 8;
    t[i][j] = Wa[(size_t)(d0 + i) * H_ + h0 + j];
  }
  __syncthreads();
#pragma unroll
  for (int jj = 0; jj < 4; jj++) {
    int r = i0 + jj * 8;
    WaT[(size_t)(h0 + r) * D_ + d0 + j] = f2bf(t[j][r]);
  }
}

// ---------------------------------------------------------------------------
// Kernel 1 (R1 rewrite): UhB[b][h] += sum_{d in slice} text[b][d]*Ua[d][h]
// Split-K: grid (H/256, B/8, D/128) = 256 blocks (was 16 -> latency-bound,
// 433us @ 0.76% occupancy). Text tile staged in LDS; Ua streamed coalesced.
// ba is applied in the k_scores epilogue instead.
// ---------------------------------------------------------------------------
__global__ void k_uh(const float* __restrict__ text, const float* __restrict__ Ua,
                     float* __restrict__ UhB) {
  __shared__ float tloc[8][128];
  const int h  = blockIdx.x * 256 + threadIdx.x;
  const int b0 = blockIdx.y * 8;
  const int d0 = blockIdx.z * 128;
  {
    int r = threadIdx.x >> 5;   // 0..7
    int c = threadIdx.x & 31;   // 0..31
#pragma unroll
    for (int j = 0; j < 4; j++)
      tloc[r][c + 32 * j] = text[(size_t)(b0 + r) * D_ + d0 + c + 32 * j];
  }
  __syncthreads();
  float acc[8] = {0.f, 0.f, 0.f, 0.f, 0.f, 0.f, 0.f, 0.f};
#pragma unroll 4
  for (int dd = 0; dd < 128; dd++) {
    float ua = Ua[(size_t)(d0 + dd) * H_ + h];
#pragma unroll
    for (int i = 0; i < 8; i++) acc[i] = fmaf(tloc[i][dd], ua, acc[i]);
  }
#pragma unroll
  for (int i = 0; i < 8; i++) atomicAdd(&UhB[(b0 + i) * H_ + h], acc[i]);
}

// ---------------------------------------------------------------------------
// Kernel 2: fused score GEMM.
// C[r][h] = frames_flat[r][:] @ Wa[:][h]   (r = b*T+t, M=32768, N=512, K=2048)
// epilogue: scores[r] += sum_h tanh(C+UhB+ba)*Va  over this block's 128 cols.
// Tile 128x128xBK64, 4 waves (2x2 of 64x64), mfma 16x16x32 bf16.
// ---------------------------------------------------------------------------
__launch_bounds__(256, 2)
__global__ void k_scores(const float* __restrict__ frames,
                         const unsigned short* __restrict__ WaT,
                         const float* __restrict__ UhB,
                         const float* __restrict__ Va,
                         const float* __restrict__ ba,
                         float* __restrict__ scores) {
  __shared__ __align__(16) unsigned short ldsA[128 * 72];
  __shared__ __align__(16) unsigned short ldsB[128 * 72];
  const int tid  = threadIdx.x;
  const int lane = tid & 63, wave = tid >> 6;
  const int wm = wave >> 1, wn = wave & 1;
  const int lr = lane & 15, q = lane >> 4;
  const int mBase = blockIdx.x * 128;   // 256 blocks: within one b (128|512)
  const int hBase = blockIdx.y * 128;   // 4 h-blocks

  floatx4 acc[4][4];
#pragma unroll
  for (int mi = 0; mi < 4; mi++)
#pragma unroll
    for (int ni = 0; ni < 4; ni++) acc[mi][ni] = (floatx4){0.f, 0.f, 0.f, 0.f};

  for (int k0 = 0; k0 < D_; k0 += 64) {
    // Stage A: frames rows, fp32 -> bf16 convert. 128 rows x 8 octets.
#pragma unroll
    for (int i = 0; i < 4; i++) {
      int task = i * 256 + tid;
      int m = task >> 3, oct = task & 7;
      const float* src = frames + (size_t)(mBase + m) * D_ + k0 + oct * 8;
      float4 p0 = ((const float4*)src)[0];
      float4 p1 = ((const float4*)src)[1];
      uint4 w;
      w.x = pack2(p0.x, p0.y); w.y = pack2(p0.z, p0.w);
      w.z = pack2(p1.x, p1.y); w.w = pack2(p1.z, p1.w);
      *reinterpret_cast<uint4*>(&ldsA[m * 72 + oct * 8]) = w;
    }
    // Stage B: WaT already bf16 + k-contiguous -> straight 16B copies.
#pragma unroll
    for (int i = 0; i < 4; i++) {
      int task = i * 256 + tid;
      int n = task >> 3, oct = task & 7;
      uint4 w = *reinterpret_cast<const uint4*>(
          WaT + (size_t)(hBase + n) * D_ + k0 + oct * 8);
      *reinterpret_cast<uint4*>(&ldsB[n * 72 + oct * 8]) = w;
    }
    __syncthreads();
#pragma unroll
    for (int kk = 0; kk < 2; kk++) {
      bf16x8 af[4], bfr[4];
#pragma unroll
      for (int mi = 0; mi < 4; mi++)
        af[mi] = *reinterpret_cast<const bf16x8*>(
            &ldsA[(wm * 64 + mi * 16 + lr) * 72 + kk * 32 + q * 8]);
#pragma unroll
      for (int ni = 0; ni < 4; ni++)
        bfr[ni] = *reinterpret_cast<const bf16x8*>(
            &ldsB[(wn * 64 + ni * 16 + lr) * 72 + kk * 32 + q * 8]);
#pragma unroll
      for (int mi = 0; mi < 4; mi++)
#pragma unroll
        for (int ni = 0; ni < 4; ni++)
          acc[mi][ni] = __builtin_amdgcn_mfma_f32_16x16x32_bf16(
              af[mi], bfr[ni], acc[mi][ni], 0, 0, 0);
    }
    __syncthreads();
  }

  // Epilogue. b is block-uniform (128-row tile never crosses b boundary).
  const int b = mBase >> 9;  // /T_
  float uhv[4], vav[4];
#pragma unroll
  for (int ni = 0; ni < 4; ni++) {
    int h = hBase + wn * 64 + ni * 16 + lr;
    uhv[ni] = UhB[b * H_ + h] + ba[h];
    vav[ni] = Va[h];
  }
  const int rowBase = mBase + wm * 64;
#pragma unroll
  for (int mi = 0; mi < 4; mi++) {
#pragma unroll
    for (int reg = 0; reg < 4; reg++) {
      float s = 0.f;
#pragma unroll
      for (int ni = 0; ni < 4; ni++) {
        float x = acc[mi][ni][reg] + uhv[ni];
        // tanh(x) = 1 - 2/(exp(2x)+1): inf-safe at both extremes
        float e = __expf(2.f * x);
        s += (1.f - 2.f / (e + 1.f)) * vav[ni];
      }
      s += __shfl_xor(s, 1, 16);
      s += __shfl_xor(s, 2, 16);
      s += __shfl_xor(s, 4, 16);
      s += __shfl_xor(s, 8, 16);
      if (lr == 0)
        atomicAdd(&scores[rowBase + mi * 16 + q * 4 + reg], s);
    }
  }
}

// ---------------------------------------------------------------------------
// Kernel 3: softmax over T per batch. grid=B, block=256 (2 elems/thread).
// ---------------------------------------------------------------------------
__global__ void k_softmax(const float* __restrict__ scores, float* __restrict__ att) {
  __shared__ float red[4];
  int b = blockIdx.x, tid = threadIdx.x;
  int lane = tid & 63, wave = tid >> 6;
  float s0 = scores[b * T_ + tid];
  float s1 = scores[b * T_ + 256 + tid];
  float mx = fmaxf(s0, s1);
#pragma unroll
  for (int off = 32; off; off >>= 1) mx = fmaxf(mx, __shfl_xor(mx, off, 64));
  if (lane == 0) red[wave] = mx;
  __syncthreads();
  mx = fmaxf(fmaxf(red[0], red[1]), fmaxf(red[2], red[3]));
  __syncthreads();
  float e0 = __expf(s0 - mx), e1 = __expf(s1 - mx);
  float sm = e0 + e1;
#pragma unroll
  for (int off = 32; off; off >>= 1) sm += __shfl_xor(sm, off, 64);
  if (lane == 0) red[wave] = sm;
  __syncthreads();
  sm = red[0] + red[1] + red[2] + red[3];
  float inv = 1.f / sm;
  att[b * T_ + tid]       = e0 * inv;
  att[b * T_ + 256 + tid] = e1 * inv;
}

// ---------------------------------------------------------------------------
// Kernel 4 (R1: +T-split x4): out[b][d] += sum_{t in slice} att*frames.
// grid (D/1024, B, 4) = 512 blocks (was 128 -> only half the CUs busy).
// d_out is memset to 0 before launch; partials via atomicAdd.
// ---------------------------------------------------------------------------
__global__ void k_wsum(const float* __restrict__ frames, const float* __restrict__ att,
                       float* __restrict__ out) {
  int b  = blockIdx.y;
  int d0 = blockIdx.x * 1024 + threadIdx.x * 4;
  int t0 = blockIdx.z * (T_ / 4);
  const float* fp = frames + (size_t)b * T_ * D_ + d0;
  const float* ap = att + b * T_;
  float4 acc = {0.f, 0.f, 0.f, 0.f};
  for (int t = t0; t < t0 + T_ / 4; t += 4) {
    float a0 = ap[t], a1 = ap[t + 1], a2 = ap[t + 2], a3 = ap[t + 3];
    float4 v0 = *(const float4*)(fp + (size_t)(t + 0) * D_);
    float4 v1 = *(const float4*)(fp + (size_t)(t + 1) * D_);
    float4 v2 = *(const float4*)(fp + (size_t)(t + 2) * D_);
    float4 v3 = *(const float4*)(fp + (size_t)(t + 3) * D_);
    acc.x += a0 * v0.x + a1 * v1.x + a2 * v2.x + a3 * v3.x;
    acc.y += a0 * v0.y + a1 * v1.y + a2 * v2.y + a3 * v3.y;
    acc.z += a0 * v0.z + a1 * v1.z + a2 * v2.z + a3 * v3.z;
    acc.w += a0 * v0.w + a1 * v1.w + a2 * v2.w + a3 * v3.w;
  }
  float* op = out + (size_t)b * D_ + d0;
  atomicAdd(op + 0, acc.x);
  atomicAdd(op + 1, acc.y);
  atomicAdd(op + 2, acc.z);
  atomicAdd(op + 3, acc.w);
}

// ---------------------------------------------------------------------------
extern "C" void kernel_launch(void* const* d_in, const int* in_sizes, int n_in,
                              void* d_out, int out_size, void* d_ws, size_t ws_size,
                              hipStream_t stream) {
  const float* frames = (const float*)d_in[0];
  const float* text   = (const float*)d_in[1];
  const float* Wa     = (const float*)d_in[2];
  const float* Ua     = (const float*)d_in[3];
  const float* Va     = (const float*)d_in[4];
  const float* ba     = (const float*)d_in[5];
  float* out = (float*)d_out;

  char* ws = (char*)d_ws;
  unsigned short* WaT = (unsigned short*)ws;                      // 2 MB
  float* UhB    = (float*)(ws + (size_t)(2u << 20));              // 128 KB
  float* scores = (float*)(ws + (size_t)(2u << 20) + (128u << 10));  // 128 KB
  float* att    = (float*)(ws + (size_t)(2u << 20) + (256u << 10));

  // Zero UhB + scores (contiguous, 256 KB) and d_out (atomic accumulation).
  (void)hipMemsetAsync(UhB, 0, (size_t)(256u << 10), stream);
  (void)hipMemsetAsync(out, 0, (size_t)B_ * D_ * sizeof(float), stream);

  k_transpose_wa<<<dim3(H_ / 32, D_ / 32), 256, 0, stream>>>(Wa, WaT);
  k_uh<<<dim3(H_ / 256, B_ / 8, D_ / 128), 256, 0, stream>>>(text, Ua, UhB);
  k_scores<<<dim3((B_ * T_) / 128, H_ / 128), 256, 0, stream>>>(frames, WaT, UhB, Va, ba, scores);
  k_softmax<<<B_, 256, 0, stream>>>(scores, att);
  k_wsum<<<dim3(D_ / 1024, B_, 4), 256, 0, stream>>>(frames, att, out);
}

// Round 3
// 579.805 us; speedup vs baseline: 1.7906x; 1.0874x over previous
//
#include <hip/hip_runtime.h>
#include <hip/hip_bf16.h>
#include <stdint.h>

// Problem: B=64, T=512, D=2048, H=512
//   Uh   = text @ Ua + ba                 [B,H]
//   s    = tanh(frames@Wa + Uh) . Va      [B,T]
//   att  = softmax_T(s)                   [B,T]
//   out  = att . frames                   [B,D]
#define B_ 64
#define T_ 512
#define D_ 2048
#define H_ 512

typedef __bf16 bf16x8 __attribute__((ext_vector_type(8)));
typedef float floatx4 __attribute__((ext_vector_type(4)));

__device__ __forceinline__ unsigned short f2bf(float f) {
  unsigned int u = __float_as_uint(f);
  return (unsigned short)((u + 0x7FFFu + ((u >> 16) & 1u)) >> 16);  // RNE
}
__device__ __forceinline__ unsigned int pack2(float a, float b) {
  return (unsigned int)f2bf(a) | ((unsigned int)f2bf(b) << 16);
}

// async global->LDS, 16B per lane, lane i lands at ldsbase + i*16
__device__ __forceinline__ void gload16(const void* g, void* l) {
  __builtin_amdgcn_global_load_lds(
      (const __attribute__((address_space(1))) void*)g,
      (__attribute__((address_space(3))) void*)l, 16, 0, 0);
}

// ---------------------------------------------------------------------------
// Kernel 0: Wa [D][H] fp32 -> WaT [H][D] bf16  (GEMM B-operand k-contiguous)
// ---------------------------------------------------------------------------
__global__ void k_transpose_wa(const float* __restrict__ Wa,
                               unsigned short* __restrict__ WaT) {
  __shared__ float t[32][33];
  int h0 = blockIdx.x * 32;
  int d0 = blockIdx.y * 32;
  int j  = threadIdx.x & 31;
  int i0 = threadIdx.x >> 5;  // 0..7
#pragma unroll
  for (int ii = 0; ii < 4; ii++) {
    int i = i0 + ii * 8;
    t[i][j] = Wa[(size_t)(d0 + i) * H_ + h0 + j];
  }
  __syncthreads();
#pragma unroll
  for (int jj = 0; jj < 4; jj++) {
    int r = i0 + jj * 8;
    WaT[(size_t)(h0 + r) * D_ + d0 + j] = f2bf(t[j][r]);
  }
}

// ---------------------------------------------------------------------------
// Kernel 0b: frames fp32 -> bf16, streaming cast (8 elems/thread).
// 67.1M elems / 8 = 8.39M threads = 32768 blocks x 256.
// ---------------------------------------------------------------------------
__global__ void k_cast(const float* __restrict__ in, unsigned short* __restrict__ out) {
  size_t i = ((size_t)blockIdx.x * 256 + threadIdx.x) * 8;
  float4 a = ((const float4*)(in + i))[0];
  float4 b = ((const float4*)(in + i))[1];
  uint4 w;
  w.x = pack2(a.x, a.y); w.y = pack2(a.z, a.w);
  w.z = pack2(b.x, b.y); w.w = pack2(b.z, b.w);
  *(uint4*)(out + i) = w;
}

// ---------------------------------------------------------------------------
// Kernel 1: split-K GEMV  UhB[b][h] += sum_{d slice} text[b][d]*Ua[d][h]
// grid (H/256, B/8, D/128) = 256 blocks. ba applied in k_scores epilogue.
// ---------------------------------------------------------------------------
__global__ void k_uh(const float* __restrict__ text, const float* __restrict__ Ua,
                     float* __restrict__ UhB) {
  __shared__ float tloc[8][128];
  const int h  = blockIdx.x * 256 + threadIdx.x;
  const int b0 = blockIdx.y * 8;
  const int d0 = blockIdx.z * 128;
  {
    int r = threadIdx.x >> 5;
    int c = threadIdx.x & 31;
#pragma unroll
    for (int j = 0; j < 4; j++)
      tloc[r][c + 32 * j] = text[(size_t)(b0 + r) * D_ + d0 + c + 32 * j];
  }
  __syncthreads();
  float acc[8] = {0.f, 0.f, 0.f, 0.f, 0.f, 0.f, 0.f, 0.f};
#pragma unroll 4
  for (int dd = 0; dd < 128; dd++) {
    float ua = Ua[(size_t)(d0 + dd) * H_ + h];
#pragma unroll
    for (int i = 0; i < 8; i++) acc[i] = fmaf(tloc[i][dd], ua, acc[i]);
  }
#pragma unroll
  for (int i = 0; i < 8; i++) atomicAdd(&UhB[(b0 + i) * H_ + h], acc[i]);
}

// ---------------------------------------------------------------------------
// Kernel 2: fused score GEMM, m97 structure.
// C[r][h] = frames[r][:] @ Wa[:][h]   (M=32768, N=512, K=2048)
// Tile 128x128xBK64, 4 waves (2x2 of 64x64), mfma 16x16x32 bf16.
// LDS: unpadded row-major, stride 64 shorts (128B) -- lane-order contiguous,
// required by global_load_lds (wave-uniform base + lane*16 scatter).
// PRECAST=true : A staged via global_load_lds from pre-cast bf16 frames.
// PRECAST=false: A staged via fp32 load + pack (ws too small fallback).
// Epilogue: scores[r] += sum_h tanh(C+UhB+ba)*Va over this block's 128 cols.
// ---------------------------------------------------------------------------
template <bool PRECAST>
__launch_bounds__(256, 2)
__global__ void k_scores(const void* __restrict__ framesAny,
                         const unsigned short* __restrict__ WaT,
                         const float* __restrict__ UhB,
                         const float* __restrict__ Va,
                         const float* __restrict__ ba,
                         float* __restrict__ scores) {
  __shared__ __align__(16) unsigned short ldsA[128 * 64];
  __shared__ __align__(16) unsigned short ldsB[128 * 64];
  const int tid  = threadIdx.x;
  const int lane = tid & 63, wave = tid >> 6;
  const int wm = wave >> 1, wn = wave & 1;
  const int lr = lane & 15, q = lane >> 4;
  const int mBase = blockIdx.x * 128;   // tiles never cross a batch boundary
  const int hBase = blockIdx.y * 128;

  // per-lane source coords for the staging DMA: 8 lanes/row, 8 octs
  const int sRow = lane >> 3, sOct = lane & 7;

  floatx4 acc[4][4];
#pragma unroll
  for (int mi = 0; mi < 4; mi++)
#pragma unroll
    for (int ni = 0; ni < 4; ni++) acc[mi][ni] = (floatx4){0.f, 0.f, 0.f, 0.f};

  for (int k0 = 0; k0 < D_; k0 += 64) {
    if (PRECAST) {
      const unsigned short* fb = (const unsigned short*)framesAny;
#pragma unroll
      for (int i = 0; i < 4; i++) {  // wave stages rows [wave*32+i*8, +8)
        int r0 = wave * 32 + i * 8;
        gload16(fb + (size_t)(mBase + r0 + sRow) * D_ + k0 + sOct * 8,
                &ldsA[r0 * 64]);
      }
    } else {
      const float* ff = (const float*)framesAny;
#pragma unroll
      for (int i = 0; i < 4; i++) {
        int task = i * 256 + tid;
        int m = task >> 3, oct = task & 7;
        const float* src = ff + (size_t)(mBase + m) * D_ + k0 + oct * 8;
        float4 p0 = ((const float4*)src)[0];
        float4 p1 = ((const float4*)src)[1];
        uint4 w;
        w.x = pack2(p0.x, p0.y); w.y = pack2(p0.z, p0.w);
        w.z = pack2(p1.x, p1.y); w.w = pack2(p1.z, p1.w);
        *reinterpret_cast<uint4*>(&ldsA[m * 64 + oct * 8]) = w;
      }
    }
#pragma unroll
    for (int i = 0; i < 4; i++) {
      int r0 = wave * 32 + i * 8;
      gload16(WaT + (size_t)(hBase + r0 + sRow) * D_ + k0 + sOct * 8,
              &ldsB[r0 * 64]);
    }
    __syncthreads();
#pragma unroll
    for (int kk = 0; kk < 2; kk++) {
      bf16x8 af[4], bfr[4];
#pragma unroll
      for (int mi = 0; mi < 4; mi++)
        af[mi] = *reinterpret_cast<const bf16x8*>(
            &ldsA[(wm * 64 + mi * 16 + lr) * 64 + kk * 32 + q * 8]);
#pragma unroll
      for (int ni = 0; ni < 4; ni++)
        bfr[ni] = *reinterpret_cast<const bf16x8*>(
            &ldsB[(wn * 64 + ni * 16 + lr) * 64 + kk * 32 + q * 8]);
#pragma unroll
      for (int mi = 0; mi < 4; mi++)
#pragma unroll
        for (int ni = 0; ni < 4; ni++)
          acc[mi][ni] = __builtin_amdgcn_mfma_f32_16x16x32_bf16(
              af[mi], bfr[ni], acc[mi][ni], 0, 0, 0);
    }
    __syncthreads();
  }

  // Epilogue. b is block-uniform (T=512 divisible by 128).
  const int b = mBase >> 9;
  float uhv[4], vav[4];
#pragma unroll
  for (int ni = 0; ni < 4; ni++) {
    int h = hBase + wn * 64 + ni * 16 + lr;
    uhv[ni] = UhB[b * H_ + h] + ba[h];
    vav[ni] = Va[h];
  }
  const int rowBase = mBase + wm * 64;
#pragma unroll
  for (int mi = 0; mi < 4; mi++) {
#pragma unroll
    for (int reg = 0; reg < 4; reg++) {
      float s = 0.f;
#pragma unroll
      for (int ni = 0; ni < 4; ni++) {
        float x = acc[mi][ni][reg] + uhv[ni];
        float e = __expf(2.f * x);               // tanh, inf-safe
        s += (1.f - 2.f / (e + 1.f)) * vav[ni];
      }
      s += __shfl_xor(s, 1, 16);
      s += __shfl_xor(s, 2, 16);
      s += __shfl_xor(s, 4, 16);
      s += __shfl_xor(s, 8, 16);
      if (lr == 0)
        atomicAdd(&scores[rowBase + mi * 16 + q * 4 + reg], s);
    }
  }
}

// ---------------------------------------------------------------------------
// Kernel 3: softmax over T per batch. grid=B, block=256.
// ---------------------------------------------------------------------------
__global__ void k_softmax(const float* __restrict__ scores, float* __restrict__ att) {
  __shared__ float red[4];
  int b = blockIdx.x, tid = threadIdx.x;
  int lane = tid & 63, wave = tid >> 6;
  float s0 = scores[b * T_ + tid];
  float s1 = scores[b * T_ + 256 + tid];
  float mx = fmaxf(s0, s1);
#pragma unroll
  for (int off = 32; off; off >>= 1) mx = fmaxf(mx, __shfl_xor(mx, off, 64));
  if (lane == 0) red[wave] = mx;
  __syncthreads();
  mx = fmaxf(fmaxf(red[0], red[1]), fmaxf(red[2], red[3]));
  __syncthreads();
  float e0 = __expf(s0 - mx), e1 = __expf(s1 - mx);
  float sm = e0 + e1;
#pragma unroll
  for (int off = 32; off; off >>= 1) sm += __shfl_xor(sm, off, 64);
  if (lane == 0) red[wave] = sm;
  __syncthreads();
  sm = red[0] + red[1] + red[2] + red[3];
  float inv = 1.f / sm;
  att[b * T_ + tid]       = e0 * inv;
  att[b * T_ + 256 + tid] = e1 * inv;
}

// ---------------------------------------------------------------------------
// Kernel 4: out[b][d] += sum_{t slice} att*frames. grid (D/1024, B, 4).
// ---------------------------------------------------------------------------
__global__ void k_wsum(const float* __restrict__ frames, const float* __restrict__ att,
                       float* __restrict__ out) {
  int b  = blockIdx.y;
  int d0 = blockIdx.x * 1024 + threadIdx.x * 4;
  int t0 = blockIdx.z * (T_ / 4);
  const float* fp = frames + (size_t)b * T_ * D_ + d0;
  const float* ap = att + b * T_;
  float4 acc = {0.f, 0.f, 0.f, 0.f};
  for (int t = t0; t < t0 + T_ / 4; t += 4) {
    float a0 = ap[t], a1 = ap[t + 1], a2 = ap[t + 2], a3 = ap[t + 3];
    float4 v0 = *(const float4*)(fp + (size_t)(t + 0) * D_);
    float4 v1 = *(const float4*)(fp + (size_t)(t + 1) * D_);
    float4 v2 = *(const float4*)(fp + (size_t)(t + 2) * D_);
    float4 v3 = *(const float4*)(fp + (size_t)(t + 3) * D_);
    acc.x += a0 * v0.x + a1 * v1.x + a2 * v2.x + a3 * v3.x;
    acc.y += a0 * v0.y + a1 * v1.y + a2 * v2.y + a3 * v3.y;
    acc.z += a0 * v0.z + a1 * v1.z + a2 * v2.z + a3 * v3.z;
    acc.w += a0 * v0.w + a1 * v1.w + a2 * v2.w + a3 * v3.w;
  }
  float* op = out + (size_t)b * D_ + d0;
  atomicAdd(op + 0, acc.x);
  atomicAdd(op + 1, acc.y);
  atomicAdd(op + 2, acc.z);
  atomicAdd(op + 3, acc.w);
}

// ---------------------------------------------------------------------------
extern "C" void kernel_launch(void* const* d_in, const int* in_sizes, int n_in,
                              void* d_out, int out_size, void* d_ws, size_t ws_size,
                              hipStream_t stream) {
  const float* frames = (const float*)d_in[0];
  const float* text   = (const float*)d_in[1];
  const float* Wa     = (const float*)d_in[2];
  const float* Ua     = (const float*)d_in[3];
  const float* Va     = (const float*)d_in[4];
  const float* ba     = (const float*)d_in[5];
  float* out = (float*)d_out;

  const size_t FRAMES_BF_BYTES = (size_t)B_ * T_ * D_ * 2;   // 128 MB
  const bool precast = ws_size >= FRAMES_BF_BYTES + (4u << 20);

  char* ws = (char*)d_ws;
  unsigned short* framesBf = (unsigned short*)ws;  // 128 MB (precast only)
  size_t off = precast ? FRAMES_BF_BYTES : 0;
  unsigned short* WaT = (unsigned short*)(ws + off);          off += (2u << 20);
  float* UhB    = (float*)(ws + off);                         off += (128u << 10);
  float* scores = (float*)(ws + off);                         off += (128u << 10);
  float* att    = (float*)(ws + off);

  (void)hipMemsetAsync(UhB, 0, (size_t)(256u << 10), stream);  // UhB + scores
  (void)hipMemsetAsync(out, 0, (size_t)B_ * D_ * sizeof(float), stream);

  k_transpose_wa<<<dim3(H_ / 32, D_ / 32), 256, 0, stream>>>(Wa, WaT);
  k_uh<<<dim3(H_ / 256, B_ / 8, D_ / 128), 256, 0, stream>>>(text, Ua, UhB);
  if (precast) {
    k_cast<<<(B_ * T_ * D_) / (256 * 8), 256, 0, stream>>>(frames, framesBf);
    k_scores<true><<<dim3((B_ * T_) / 128, H_ / 128), 256, 0, stream>>>(
        framesBf, WaT, UhB, Va, ba, scores);
  } else {
    k_scores<false><<<dim3((B_ * T_) / 128, H_ / 128), 256, 0, stream>>>(
        frames, WaT, UhB, Va, ba, scores);
  }
  k_softmax<<<B_, 256, 0, stream>>>(scores, att);
  k_wsum<<<dim3(D_ / 1024, B_, 4), 256, 0, stream>>>(frames, att, out);
}